// Round 2
// baseline (242.764 us; speedup 1.0000x reference)
//
#include <hip/hip_runtime.h>

// NetVladCNN: B=64, D=512, H=W=32 (N=1024), K=64
// K0 : pack w f32 -> bf16 image [16 dblk][64 k][32 d] (unpadded, 64 KB)
// K1 : feat = w @ x[b] per (b, 64n-tile). grid 1024 (4 blocks/CU). x staged via
//      glds 4-buffer ring, 3 stages in flight (counted vmcnt, pinned issue
//      order); w-frags direct from global (L2-hot) via depth-3 reg ring.
// K1b: softmax over H; vectorized; writes a bf16 unpadded image [h][k][32 w]
// K2 : V = a @ x^T - 32*c; BARRIER-FREE + LDS-FREE: a-frags direct from global
//      (same-XCD L2 reuse across the 8 dt-blocks of a b), x depth-4 reg ring,
//      fully unrolled; fused L2-normalize. -> yw (B,K,D)
// K3 : transpose -> out (D,K,B)

typedef __attribute__((ext_vector_type(8))) short short8;
typedef __attribute__((ext_vector_type(4))) float f32x4;
typedef unsigned short u16;
typedef unsigned int u32;

union S8u { u32 q[4]; short8 s; };

__device__ __forceinline__ u32 pk2(float lo, float hi) {  // RNE bf16 pair pack
  union { float f; u32 u; } a, b; a.f = lo; b.f = hi;
  u32 xl = (a.u + 0x7fffu + ((a.u >> 16) & 1u)) >> 16;
  u32 xh = (b.u + 0x7fffu + ((b.u >> 16) & 1u)) & 0xffff0000u;
  return xl | xh;
}

typedef const __attribute__((address_space(1))) u32 GU32;
typedef __attribute__((address_space(3))) u32 LU32;
__device__ __forceinline__ void glds16(const void* g, void* l) {
  __builtin_amdgcn_global_load_lds((GU32*)g, (LU32*)l, 16, 0, 0);
}

// ---------------- K0: pack w into unpadded bf16 image ----------------
// wsw image: [i=d-block 16][k 64][32 d] u16 = 64 KB
__global__ __launch_bounds__(256) void k0_packw(
    const float* __restrict__ w, u16* __restrict__ wsw)
{
  const int tg = blockIdx.x * 256 + threadIdx.x;   // 8192 threads
  const int dd4 = tg & 7, i = (tg >> 3) & 15, k = tg >> 7;
  f32x4 v = *(const f32x4*)(w + k * 512 + i * 32 + dd4 * 4);
  u32* dst = (u32*)(wsw + (size_t)(i * 64 + k) * 32 + dd4 * 4);
  dst[0] = pk2(v[0], v[1]);
  dst[1] = pk2(v[2], v[3]);
}

// ---------------- K1: features GEMM (deep glds ring) ----------------
// grid 1024 = (nt 16)*(b 64); block 256 = 4 waves; tile 64k x 64n, K=512.
__global__ __launch_bounds__(256, 3) void k1_features(
    const float* __restrict__ x, const u16* __restrict__ wsw,
    float* __restrict__ feat)
{
  const int blk = blockIdx.x;
  const int b = blk & 63, nt = blk >> 6;           // XCD = b%8
  const int nb = nt * 64;
  const int tid = threadIdx.x, lane = tid & 63, wv = tid >> 6;
  const int row = lane & 15, q = lane >> 4;

  __shared__ __align__(16) float xs[4][32][64];    // 32 KB, 4-stage ring

  const char* xbase = (const char*)(x + ((size_t)b << 19) + nb);
  const int r0 = tid >> 4, cb = (tid & 15) * 16;   // 2 uniform glds per lane

  f32x4 acc[4];
#pragma unroll
  for (int mt = 0; mt < 4; mt++) acc[mt] = (f32x4){0.f, 0.f, 0.f, 0.f};

  short8 wf[4][4];                                 // w-frag ring, 3 in flight

#define STAGE1(s)                                                              \
  {                                                                            \
    char* lx = (char*)&xs[(s) & 3][0][0];                                      \
    const char* gx = xbase + (size_t)(s) * 131072;                             \
    glds16(gx + (size_t)r0 * 4096 + cb, lx + r0 * 256 + cb);                   \
    glds16(gx + (size_t)(r0 + 16) * 4096 + cb, lx + (r0 + 16) * 256 + cb);     \
  }
#define LOADW(s)                                                               \
  {                                                                            \
    _Pragma("unroll")                                                          \
    for (int mt = 0; mt < 4; mt++)                                             \
      wf[(s) & 3][mt] = *(const short8*)(                                      \
          wsw + (size_t)(((s) * 64 + mt * 16 + row) * 32 + q * 8));            \
  }

  // pinned prologue: G0 W0 G1 W1 G2 W2  (per lane: 2,4,2,4,2,4 vm ops)
  STAGE1(0); __builtin_amdgcn_sched_barrier(0);
  LOADW(0);  __builtin_amdgcn_sched_barrier(0);
  STAGE1(1); __builtin_amdgcn_sched_barrier(0);
  LOADW(1);  __builtin_amdgcn_sched_barrier(0);
  STAGE1(2); __builtin_amdgcn_sched_barrier(0);
  LOADW(2);  __builtin_amdgcn_sched_barrier(0);

#pragma unroll
  for (int i = 0; i < 16; i++) {
    // counted drain for stage i's own glds (ops issued after G(i)):
    // steady: W(i)4 + 2*(G+W)12 = 16 ; i==14: 10 ; i==15: 4
    if (i == 14)      asm volatile("s_waitcnt vmcnt(10)" ::: "memory");
    else if (i == 15) asm volatile("s_waitcnt vmcnt(4)" ::: "memory");
    else              asm volatile("s_waitcnt vmcnt(16)" ::: "memory");
    __builtin_amdgcn_s_barrier();
    __builtin_amdgcn_sched_barrier(0);
    if (i < 13) {
      STAGE1(i + 3); __builtin_amdgcn_sched_barrier(0);
      LOADW(i + 3);  __builtin_amdgcn_sched_barrier(0);
    }

    // B-frag: pack 8 d-consecutive x values for this wave's n column
    const float* xr = &xs[i & 3][0][wv * 16 + row];
    const int d8 = q * 8;
    float v0 = xr[(d8 + 0) * 64], v1 = xr[(d8 + 1) * 64];
    float v2 = xr[(d8 + 2) * 64], v3 = xr[(d8 + 3) * 64];
    float v4 = xr[(d8 + 4) * 64], v5 = xr[(d8 + 5) * 64];
    float v6 = xr[(d8 + 6) * 64], v7 = xr[(d8 + 7) * 64];
    S8u t;
    t.q[0] = pk2(v0, v1); t.q[1] = pk2(v2, v3);
    t.q[2] = pk2(v4, v5); t.q[3] = pk2(v6, v7);
    const short8 bfv = t.s;
#pragma unroll
    for (int mt = 0; mt < 4; mt++)
      acc[mt] = __builtin_amdgcn_mfma_f32_16x16x32_bf16(wf[i & 3][mt], bfv, acc[mt], 0, 0, 0);
  }
#undef STAGE1
#undef LOADW

  float* fb = feat + ((size_t)b << 16);
  const int nbw = nb + wv * 16 + row;
#pragma unroll
  for (int mt = 0; mt < 4; mt++)
#pragma unroll
    for (int r = 0; r < 4; r++)     // C layout: col=lane&15 (n), row=q*4+r (k)
      fb[(mt * 16 + q * 4 + r) * 1024 + nbw] = acc[mt][r];
}

// ---------------- K1b: softmax over H -> unpadded a image ----------------
// apad image: [b][h 32][k 64][w 32] u16 (64 B rows)
__global__ __launch_bounds__(256) void k1b_softmax(
    const float* __restrict__ feat, u16* __restrict__ apad)
{
  const int tid = threadIdx.x, wv = tid >> 6, lane = tid & 63;
  const int rid = blockIdx.x * 4 + wv;         // rid = b*64 + k
  const int b = rid >> 6, k = rid & 63;
  const float* f = feat + ((size_t)rid << 10);
  const int wl = (lane & 7) * 4;               // 4 w-columns per lane
  const int hq = lane >> 3;                    // h = hq + r*8

  f32x4 v[4];
#pragma unroll
  for (int r = 0; r < 4; r++)
    v[r] = *(const f32x4*)(f + (hq + r * 8) * 32 + wl);

  f32x4 m = v[0];
#pragma unroll
  for (int r = 1; r < 4; r++)
#pragma unroll
    for (int c = 0; c < 4; c++) m[c] = fmaxf(m[c], v[r][c]);
#pragma unroll
  for (int mk = 8; mk <= 32; mk <<= 1)
#pragma unroll
    for (int c = 0; c < 4; c++) m[c] = fmaxf(m[c], __shfl_xor(m[c], mk));

  f32x4 s = (f32x4){0.f, 0.f, 0.f, 0.f};
#pragma unroll
  for (int r = 0; r < 4; r++)
#pragma unroll
    for (int c = 0; c < 4; c++) { v[r][c] = __expf(v[r][c] - m[c]); s[c] += v[r][c]; }
#pragma unroll
  for (int mk = 8; mk <= 32; mk <<= 1)
#pragma unroll
    for (int c = 0; c < 4; c++) s[c] += __shfl_xor(s[c], mk);

  f32x4 inv;
#pragma unroll
  for (int c = 0; c < 4; c++) inv[c] = 1.0f / s[c];

#pragma unroll
  for (int r = 0; r < 4; r++) {
    const int h = hq + r * 8;
    u32* dst = (u32*)(apad + ((size_t)(b * 32 + h) * 64 + k) * 32 + wl);
    dst[0] = pk2(v[r][0] * inv[0], v[r][1] * inv[1]);
    dst[1] = pk2(v[r][2] * inv[2], v[r][3] * inv[3]);
  }
}

// ---------------- K2: aggregation + fused normalize (no LDS, no barriers) --
// grid 512 = (dt 8)*(b 64); block 256 = 4 waves; wave: 64k x 16d; 32 n-iters.
__global__ __launch_bounds__(256, 2) void k2_aggregate(
    const float* __restrict__ x, const u16* __restrict__ apad,
    const float* __restrict__ cc, float* __restrict__ yw)
{
  const int blk = blockIdx.x;
  const int b = blk & 63, dt = blk >> 6;       // XCD = b%8 (same as K1b's b)
  const int tid = threadIdx.x, lane = tid & 63, wv = tid >> 6;
  const int row = lane & 15, q = lane >> 4;

  const float* px0 = x + ((size_t)b << 19) + (size_t)(dt * 64 + wv * 16 + row) * 1024 + q * 8;
  const u16* ab = apad + ((size_t)b << 16) + (size_t)row * 32 + q * 8;

  f32x4 acc[4];
#pragma unroll
  for (int mt = 0; mt < 4; mt++) acc[mt] = (f32x4){0.f, 0.f, 0.f, 0.f};

  f32x4 xp0[4], xp1[4];                        // x ring, depth 4 (HBM)
  short8 ap[3][4];                             // a ring, depth 3 slots (L2)
#pragma unroll
  for (int j = 0; j < 4; j++) {
    xp0[j] = *(const f32x4*)(px0 + j * 32);
    xp1[j] = *(const f32x4*)(px0 + j * 32 + 4);
  }
#pragma unroll
  for (int j = 0; j < 2; j++)
#pragma unroll
    for (int mt = 0; mt < 4; mt++)
      ap[j][mt] = *(const short8*)(ab + (size_t)j * 2048 + mt * 512);

#pragma unroll
  for (int i = 0; i < 32; i++) {
    const f32x4 c0 = xp0[i & 3], c1 = xp1[i & 3];
    S8u t;
    t.q[0] = pk2(c0[0], c0[1]); t.q[1] = pk2(c0[2], c0[3]);
    t.q[2] = pk2(c1[0], c1[1]); t.q[3] = pk2(c1[2], c1[3]);
    const short8 bfv = t.s;
#pragma unroll
    for (int mt = 0; mt < 4; mt++)
      acc[mt] = __builtin_amdgcn_mfma_f32_16x16x32_bf16(ap[i % 3][mt], bfv, acc[mt], 0, 0, 0);
    if (i + 4 < 32) {
      xp0[i & 3] = *(const f32x4*)(px0 + (i + 4) * 32);
      xp1[i & 3] = *(const f32x4*)(px0 + (i + 4) * 32 + 4);
    }
    if (i + 2 < 32) {
#pragma unroll
      for (int mt = 0; mt < 4; mt++)
        ap[(i + 2) % 3][mt] = *(const short8*)(ab + (size_t)(i + 2) * 2048 + mt * 512);
    }
  }

  // epilogue: lane holds 16 k's for d = dcol; norm over k wave-local (quads)
  const int dcol = dt * 64 + wv * 16 + row;
  float v[16]; float ss = 0.f;
#pragma unroll
  for (int mt = 0; mt < 4; mt++)
#pragma unroll
    for (int r = 0; r < 4; r++) {
      const int k = mt * 16 + q * 4 + r;
      const float tv = acc[mt][r] - 32.0f * cc[k * 512 + dcol];  // Sum_n a = 32 exact
      v[mt * 4 + r] = tv; ss += tv * tv;
    }
  ss += __shfl_xor(ss, 16);
  ss += __shfl_xor(ss, 32);
  const float rn = 1.0f / fmaxf(sqrtf(ss), 1e-12f);  // 2nd normalize is identity
  float* yb = yw + ((size_t)b << 15) + dcol;
#pragma unroll
  for (int mt = 0; mt < 4; mt++)
#pragma unroll
    for (int r = 0; r < 4; r++)
      yb[(size_t)(mt * 16 + q * 4 + r) << 9] = v[mt * 4 + r] * rn;
}

// ---------------- K3: (B,K,D) -> (D,K,B) ----------------
__global__ __launch_bounds__(256) void k3_transpose(
    const float* __restrict__ yw, float* __restrict__ out)
{
  const int blk = blockIdx.x;
  const int k = blk & 63;
  const int dt = blk >> 6;
  const int d0 = dt * 64;
  const int tid = threadIdx.x;
  __shared__ float T[64][68];
  {
    const int bl = tid >> 2, seg = tid & 3;
    const float* src = yw + (size_t)bl * 32768 + k * 512 + d0 + seg * 16;
#pragma unroll
    for (int i = 0; i < 4; i++) {
      f32x4 v = *(const f32x4*)(src + i * 4);
#pragma unroll
      for (int jj = 0; jj < 4; jj++) T[seg * 16 + i * 4 + jj][bl] = v[jj];
    }
  }
  __syncthreads();
  {
    const int dl = tid >> 2, bseg = tid & 3;
    float* dst = out + (size_t)(d0 + dl) * 4096 + k * 64 + bseg * 16;
    const float* srcT = &T[dl][bseg * 16];
#pragma unroll
    for (int i = 0; i < 4; i++)
      *(f32x4*)(dst + i * 4) = *(const f32x4*)(srcT + i * 4);
  }
}

extern "C" void kernel_launch(void* const* d_in, const int* in_sizes, int n_in,
                              void* d_out, int out_size, void* d_ws, size_t ws_size,
                              hipStream_t stream) {
  const float* x = (const float*)d_in[0];
  const float* w = (const float*)d_in[1];
  const float* c = (const float*)d_in[2];
  float* out = (float*)d_out;
  char* ws = (char*)d_ws;
  float* feat = (float*)ws;                                  // 16 MiB f32 logits
  u16*   apad = (u16*)(ws + (size_t)16 * 1024 * 1024);       //  8 MiB a image
  float* yw   = (float*)(ws + (size_t)26 * 1024 * 1024);     //  8 MiB (B,K,D)
  u16*   wsw  = (u16*)(ws + (size_t)34 * 1024 * 1024);       // 64 KiB w image
  k0_packw    <<<dim3(32),   dim3(256), 0, stream>>>(w, wsw);
  k1_features <<<dim3(1024), dim3(256), 0, stream>>>(x, wsw, feat);
  k1b_softmax <<<dim3(1024), dim3(256), 0, stream>>>(feat, apad);
  k2_aggregate<<<dim3(512),  dim3(256), 0, stream>>>(x, apad, c, yw);
  k3_transpose<<<dim3(512),  dim3(256), 0, stream>>>(yw, out);
}